// Round 6
// baseline (1480.957 us; speedup 1.0000x reference)
//
#include <hip/hip_runtime.h>
#include <hip/hip_bf16.h>
#include <math.h>

// ---------------- problem constants ----------------
#define BB 32
#define NN 512
#define BN 16384          // BB*NN
#define DD 1024
#define HID 512
#define G4 2048           // 4*HID
#define HLEN 15
#define IND 4
#define EPS 1e-5f
#define RPB 64            // rows per block
#define HPAD 520          // padded h LDS stride (bf16): 1040B = 260 words == 4 mod 32
#define SPAD 1032         // padded hrel stage stride

typedef __bf16 v8bf __attribute__((ext_vector_type(8)));
typedef float  v4f  __attribute__((ext_vector_type(4)));

// fast transcendentals: v_exp_f32 + v_rcp_f32 (rel err ~1e-6)
#define LOG2E 1.44269504f
__device__ __forceinline__ float sigmf(float x) {
    return __builtin_amdgcn_rcpf(1.0f + __builtin_amdgcn_exp2f(-LOG2E * x));
}
__device__ __forceinline__ float tanh_fast(float x) {
    return 1.0f - 2.0f * __builtin_amdgcn_rcpf(1.0f + __builtin_amdgcn_exp2f(2.0f * LOG2E * x));
}

// ---------------- weight prep ----------------
// whh_b: gate-interleaved (row j' = u*4+gi) bf16 2048x512; wrel_b: bf16 1024x512;
// wih_i: interleaved fp32 2048x4; bsum: b_ih+b_hh interleaved fp32 2048.
__global__ void convert_w(const float* __restrict__ Whh, const float* __restrict__ Wrel,
                          const float* __restrict__ Wih, const float* __restrict__ bih,
                          const float* __restrict__ bhh,
                          __bf16* __restrict__ whh_b, __bf16* __restrict__ wrel_b,
                          float* __restrict__ wih_i, float* __restrict__ bsum) {
    int i = blockIdx.x * 256 + threadIdx.x;
    if (i < G4 * HID) {
        int jp = i >> 9, k = i & 511;
        int uu = jp >> 2, gi = jp & 3;
        whh_b[i] = (__bf16)Whh[(size_t)(gi * HID + uu) * HID + k];
    }
    if (i < DD * HID) wrel_b[i] = (__bf16)Wrel[i];
    if (i < G4) {
        int uu = i >> 2, gi = i & 3;
        int src = gi * HID + uu;
        wih_i[i * 4 + 0] = Wih[src * 4 + 0];
        wih_i[i * 4 + 1] = Wih[src * 4 + 1];
        wih_i[i * 4 + 2] = Wih[src * 4 + 2];
        wih_i[i * 4 + 3] = Wih[src * 4 + 3];
        bsum[i] = bih[src] + bhh[src];
    }
}

// ---------------- persistent mega-kernel ----------------
// 256 blocks x 256 threads; block owns rows [blk*64, +64) for the whole pipeline.
// Per step: gates^T(2048 x 64) = whh_i(2048x512) @ h^T; waves split M (512 gate-rows each).
// c in VGPRs (lane-local via C/D layout), h in dbuf LDS. Then proj + gate-mix + LN.
__global__ __launch_bounds__(256, 1) void lstm_mega(
        const float* __restrict__ tokens, const float* __restrict__ traj,
        const float* __restrict__ habs_in,
        const float* __restrict__ es, const float* __restrict__ gc,
        const __bf16* __restrict__ whh, const __bf16* __restrict__ wrel,
        const float* __restrict__ wih_i, const float* __restrict__ bsum,
        const float* __restrict__ W_g1, const float* __restrict__ b_g1,
        const float* __restrict__ W_g2, const float* __restrict__ b_g2,
        const float* __restrict__ W_abs, const float* __restrict__ gamma,
        const float* __restrict__ beta, float* __restrict__ out) {
    __shared__ __bf16 hbuf[2][RPB * HPAD];    // 2 x 66560 B = 133120 B -> 1 block/CU

    const int blk  = blockIdx.x;
    const int tid  = threadIdx.x;
    const int lane = tid & 63;
    const int w    = tid >> 6;
    const int q    = lane >> 4;
    const int col  = lane & 15;
    const int row0 = blk * RPB;

    // per-batch alpha: whole block lies in one batch (64 | 512)
    float alpha;
    {
        const int bb = blk >> 3;
        float c0 = es[bb], c1 = gc[bb], ga = b_g2[0];
        for (int k = 0; k < 16; ++k) {
            float hk = fmaxf(c0 * W_g1[2 * k] + c1 * W_g1[2 * k + 1] + b_g1[k], 0.0f);
            ga += hk * W_g2[k];
        }
        alpha = 1.0f / (1.0f + expf(-ga));
    }

    // c state: lane-local, [chunk][mt][nt] -> unit w*128+ch*16+mt*4+q, row nt*16+col
    float creg[8][4][4];
    #pragma unroll
    for (int a = 0; a < 8; ++a)
        #pragma unroll
        for (int bq = 0; bq < 4; ++bq)
            #pragma unroll
            for (int cq = 0; cq < 4; ++cq) creg[a][bq][cq] = 0.0f;

    // ---------------- 15 recurrent steps ----------------
    for (int t = 0; t < HLEN; ++t) {
        float4 x4[4];
        #pragma unroll
        for (int nt = 0; nt < 4; ++nt)
            x4[nt] = *(const float4*)(traj + (size_t)(row0 + nt * 16 + col) * (HLEN * IND) + t * IND);

        const __bf16* rbuf = hbuf[(t + 1) & 1];   // h(t), written at step t-1
        __bf16*       wbuf = hbuf[t & 1];         // h(t+1)

        #pragma unroll
        for (int ch = 0; ch < 8; ++ch) {
            v4f acc[4][4] = {};
            if (t > 0) {
                const __bf16* ap[4];
                const __bf16* bp[4];
                #pragma unroll
                for (int mt = 0; mt < 4; ++mt)
                    ap[mt] = whh + ((size_t)(w * 512 + ch * 64 + mt * 16 + col) * HID + q * 8);
                #pragma unroll
                for (int nt = 0; nt < 4; ++nt)
                    bp[nt] = rbuf + (size_t)(nt * 16 + col) * HPAD + q * 8;

                v8bf a_c[4], b_c[4];
                #pragma unroll
                for (int mt = 0; mt < 4; ++mt) a_c[mt] = *(const v8bf*)(ap[mt]);
                #pragma unroll
                for (int nt = 0; nt < 4; ++nt) b_c[nt] = *(const v8bf*)(bp[nt]);

                #pragma unroll 1
                for (int ks = 0; ks < 16; ++ks) {
                    v8bf a_n[4], b_n[4];
                    if (ks < 15) {
                        #pragma unroll
                        for (int mt = 0; mt < 4; ++mt) a_n[mt] = *(const v8bf*)(ap[mt] + (ks + 1) * 32);
                        #pragma unroll
                        for (int nt = 0; nt < 4; ++nt) b_n[nt] = *(const v8bf*)(bp[nt] + (ks + 1) * 32);
                    }
                    #pragma unroll
                    for (int mt = 0; mt < 4; ++mt)
                        #pragma unroll
                        for (int nt = 0; nt < 4; ++nt)
                            acc[mt][nt] = __builtin_amdgcn_mfma_f32_16x16x32_bf16(a_c[mt], b_c[nt], acc[mt][nt], 0, 0, 0);
                    if (ks < 15) {
                        #pragma unroll
                        for (int mt = 0; mt < 4; ++mt) a_c[mt] = a_n[mt];
                        #pragma unroll
                        for (int nt = 0; nt < 4; ++nt) b_c[nt] = b_n[nt];
                    }
                }
            }
            // lane-local cell update: acc regs 0..3 = gates i,f,g,o of unit u for row nt*16+col
            #pragma unroll
            for (int mt = 0; mt < 4; ++mt) {
                const int u = w * 128 + ch * 16 + mt * 4 + q;
                const float* wp = wih_i + (size_t)u * 16;
                float4 wv0 = *(const float4*)(wp);
                float4 wv1 = *(const float4*)(wp + 4);
                float4 wv2 = *(const float4*)(wp + 8);
                float4 wv3 = *(const float4*)(wp + 12);
                float4 bs  = *(const float4*)(bsum + (size_t)u * 4);
                #pragma unroll
                for (int nt = 0; nt < 4; ++nt) {
                    float4 x = x4[nt];
                    float g0 = acc[mt][nt][0] + bs.x + wv0.x * x.x + wv0.y * x.y + wv0.z * x.z + wv0.w * x.w;
                    float g1 = acc[mt][nt][1] + bs.y + wv1.x * x.x + wv1.y * x.y + wv1.z * x.z + wv1.w * x.w;
                    float g2 = acc[mt][nt][2] + bs.z + wv2.x * x.x + wv2.y * x.y + wv2.z * x.z + wv2.w * x.w;
                    float g3 = acc[mt][nt][3] + bs.w + wv3.x * x.x + wv3.y * x.y + wv3.z * x.z + wv3.w * x.w;
                    float cn = sigmf(g1) * creg[ch][mt][nt] + sigmf(g0) * tanh_fast(g2);
                    creg[ch][mt][nt] = cn;
                    wbuf[(size_t)(nt * 16 + col) * HPAD + u] = (__bf16)(sigmf(g3) * tanh_fast(cn));
                }
            }
        }
        __syncthreads();   // h(t+1) fully published before step t+1 reads it
    }

    // ---------------- projection + gate-mix + LayerNorm ----------------
    // final h (h_15) is in hbuf[0] (t=14 wrote buf[0]); stage hrel in hbuf[1]
    const __bf16* hfin  = hbuf[0];
    __bf16*       stage = hbuf[1];

    for (int p = 0; p < 2; ++p) {            // two passes of 32 rows
        if (p) __syncthreads();              // pass0 LN reads done before pass1 stage writes
        #pragma unroll
        for (int ch = 0; ch < 4; ++ch) {     // wave's d-range: w*256 + ch*64
            v4f acc[4][2] = {};
            const __bf16* ap[4];
            const __bf16* bp[2];
            #pragma unroll
            for (int mt = 0; mt < 4; ++mt)
                ap[mt] = wrel + ((size_t)(w * 256 + ch * 64 + mt * 16 + col) * HID + q * 8);
            #pragma unroll
            for (int n2 = 0; n2 < 2; ++n2)
                bp[n2] = hfin + (size_t)(p * 32 + n2 * 16 + col) * HPAD + q * 8;

            v8bf a_c[4], b_c[2];
            #pragma unroll
            for (int mt = 0; mt < 4; ++mt) a_c[mt] = *(const v8bf*)(ap[mt]);
            #pragma unroll
            for (int n2 = 0; n2 < 2; ++n2) b_c[n2] = *(const v8bf*)(bp[n2]);

            #pragma unroll 1
            for (int ks = 0; ks < 16; ++ks) {
                v8bf a_n[4], b_n[2];
                if (ks < 15) {
                    #pragma unroll
                    for (int mt = 0; mt < 4; ++mt) a_n[mt] = *(const v8bf*)(ap[mt] + (ks + 1) * 32);
                    #pragma unroll
                    for (int n2 = 0; n2 < 2; ++n2) b_n[n2] = *(const v8bf*)(bp[n2] + (ks + 1) * 32);
                }
                #pragma unroll
                for (int mt = 0; mt < 4; ++mt)
                    #pragma unroll
                    for (int n2 = 0; n2 < 2; ++n2)
                        acc[mt][n2] = __builtin_amdgcn_mfma_f32_16x16x32_bf16(a_c[mt], b_c[n2], acc[mt][n2], 0, 0, 0);
                if (ks < 15) {
                    #pragma unroll
                    for (int mt = 0; mt < 4; ++mt) a_c[mt] = a_n[mt];
                    #pragma unroll
                    for (int n2 = 0; n2 < 2; ++n2) b_c[n2] = b_n[n2];
                }
            }
            #pragma unroll
            for (int mt = 0; mt < 4; ++mt)
                #pragma unroll
                for (int n2 = 0; n2 < 2; ++n2)
                    #pragma unroll
                    for (int r = 0; r < 4; ++r) {
                        int d = w * 256 + ch * 64 + mt * 16 + q * 4 + r;
                        stage[(size_t)(n2 * 16 + col) * SPAD + d] = (__bf16)acc[mt][n2][r];
                    }
        }
        __syncthreads();

        // LayerNorm: wave w handles local rows w*8 .. w*8+7, lanes split D (16 each)
        for (int rr = 0; rr < 8; ++rr) {
            const int rl   = w * 8 + rr;
            const int grow = row0 + p * 32 + rl;
            const float a0 = habs_in[(size_t)grow * 2];
            const float a1 = habs_in[(size_t)grow * 2 + 1];
            const int d0   = lane * 16;

            v8bf h0v = *(const v8bf*)(stage + (size_t)rl * SPAD + d0);
            v8bf h1v = *(const v8bf*)(stage + (size_t)rl * SPAD + d0 + 8);

            float xv[16];
            float s = 0.0f;
            #pragma unroll
            for (int g = 0; g < 4; ++g) {
                float4 tk = *(const float4*)(tokens + (size_t)grow * DD + d0 + g * 4);
                float4 wa = *(const float4*)(W_abs + (size_t)(d0 + g * 4) * 2);
                float4 wb = *(const float4*)(W_abs + (size_t)(d0 + g * 4) * 2 + 4);
                float hr0 = (g < 2) ? (float)h0v[g * 4 + 0] : (float)h1v[(g - 2) * 4 + 0];
                float hr1 = (g < 2) ? (float)h0v[g * 4 + 1] : (float)h1v[(g - 2) * 4 + 1];
                float hr2 = (g < 2) ? (float)h0v[g * 4 + 2] : (float)h1v[(g - 2) * 4 + 2];
                float hr3 = (g < 2) ? (float)h0v[g * 4 + 3] : (float)h1v[(g - 2) * 4 + 3];
                xv[g * 4 + 0] = tk.x + alpha * hr0 + (1.0f - alpha) * (a0 * wa.x + a1 * wa.y);
                xv[g * 4 + 1] = tk.y + alpha * hr1 + (1.0f - alpha) * (a0 * wa.z + a1 * wa.w);
                xv[g * 4 + 2] = tk.z + alpha * hr2 + (1.0f - alpha) * (a0 * wb.x + a1 * wb.y);
                xv[g * 4 + 3] = tk.w + alpha * hr3 + (1.0f - alpha) * (a0 * wb.z + a1 * wb.w);
                s += xv[g * 4 + 0] + xv[g * 4 + 1] + xv[g * 4 + 2] + xv[g * 4 + 3];
            }
            #pragma unroll
            for (int off = 32; off > 0; off >>= 1) s += __shfl_down(s, off);
            float mu = __shfl(s, 0) * (1.0f / DD);

            float vs = 0.0f;
            #pragma unroll
            for (int i = 0; i < 16; ++i) { float d = xv[i] - mu; vs += d * d; }
            #pragma unroll
            for (int off = 32; off > 0; off >>= 1) vs += __shfl_down(vs, off);
            float rstd = rsqrtf(__shfl(vs, 0) * (1.0f / DD) + EPS);

            #pragma unroll
            for (int g = 0; g < 4; ++g) {
                float4 gm = *(const float4*)(gamma + d0 + g * 4);
                float4 bt = *(const float4*)(beta + d0 + g * 4);
                float4 o;
                o.x = (xv[g * 4 + 0] - mu) * rstd * gm.x + bt.x;
                o.y = (xv[g * 4 + 1] - mu) * rstd * gm.y + bt.y;
                o.z = (xv[g * 4 + 2] - mu) * rstd * gm.z + bt.z;
                o.w = (xv[g * 4 + 3] - mu) * rstd * gm.w + bt.w;
                *(float4*)(out + (size_t)grow * DD + d0 + g * 4) = o;
            }
        }
    }
}

// ---------------- host launch ----------------
extern "C" void kernel_launch(void* const* d_in, const int* in_sizes, int n_in,
                              void* d_out, int out_size, void* d_ws, size_t ws_size,
                              hipStream_t stream) {
    const float* tokens   = (const float*)d_in[0];
    const float* traj     = (const float*)d_in[1];
    const float* habs     = (const float*)d_in[2];
    const float* espeed   = (const float*)d_in[3];
    const float* gconf    = (const float*)d_in[4];
    const float* W_ih     = (const float*)d_in[5];
    const float* W_hh     = (const float*)d_in[6];
    const float* b_ih     = (const float*)d_in[7];
    const float* b_hh     = (const float*)d_in[8];
    const float* W_rel    = (const float*)d_in[9];
    const float* W_abs    = (const float*)d_in[10];
    const float* W_g1     = (const float*)d_in[11];
    const float* b_g1     = (const float*)d_in[12];
    const float* W_g2     = (const float*)d_in[13];
    const float* b_g2     = (const float*)d_in[14];
    const float* gamma    = (const float*)d_in[15];
    const float* beta     = (const float*)d_in[16];
    float* out = (float*)d_out;

    char* ws = (char*)d_ws;
    size_t off = 0;
    __bf16* whh_b  = (__bf16*)(ws + off); off += (size_t)G4 * HID * 2;     // 2 MB
    __bf16* wrel_b = (__bf16*)(ws + off); off += (size_t)DD * HID * 2;     // 1 MB
    float*  wih_i  = (float*)(ws + off);  off += (size_t)G4 * 4 * 4;       // 32 KB
    float*  bsum   = (float*)(ws + off);  off += (size_t)G4 * 4;           // 8 KB

    convert_w<<<(G4 * HID + 255) / 256, 256, 0, stream>>>(W_hh, W_rel, W_ih, b_ih, b_hh,
                                                          whh_b, wrel_b, wih_i, bsum);
    lstm_mega<<<BN / RPB, 256, 0, stream>>>(tokens, traj, habs, espeed, gconf,
                                            whh_b, wrel_b, wih_i, bsum,
                                            W_g1, b_g1, W_g2, b_g2, W_abs,
                                            gamma, beta, out);
}